// Round 1
// baseline (444.741 us; speedup 1.0000x reference)
//
#include <hip/hip_runtime.h>

// EMA + gated blend, (B,L,C) = (32,4096,512) fp32.
// trend[l] = 0.7*x[l] + 0.3*trend[l-1];  out = g*(x-trend) + (1-g)*trend.
// The carry decays by 0.3/step -> influence beyond ~15 steps is < 1.4e-8,
// so we parallelize the scan: each thread owns a CH-length chunk of L and
// warms up the carry over an H-element halo seeded with x[l0-H].
// Error bound ~ 0.3^(H-1) * O(1) ~ 5e-9, vs 5.4e-2 absmax threshold.

constexpr int B   = 32;
constexpr int L   = 4096;
constexpr int C   = 512;
constexpr int CV  = C / 4;      // float4 groups along C = 128
constexpr int CH  = 128;        // chunk length along L
constexpr int NCH = L / CH;     // 32 chunks
constexpr int H   = 16;         // halo warm-up length
constexpr float ALPHA = 0.7f;

__device__ __forceinline__ float4 ema_step(float4 t, float4 xv, float a, float na) {
    float4 r;
    r.x = fmaf(a, xv.x, na * t.x);
    r.y = fmaf(a, xv.y, na * t.y);
    r.z = fmaf(a, xv.z, na * t.z);
    r.w = fmaf(a, xv.w, na * t.w);
    return r;
}

__global__ __launch_bounds__(256) void STAR_47605417509306_kernel(
        const float4* __restrict__ x, const float* __restrict__ gate,
        float4* __restrict__ out) {
    const int tid   = blockIdx.x * blockDim.x + threadIdx.x;
    const int c4    = tid & (CV - 1);          // fastest-varying -> coalesced
    const int rest  = tid / CV;
    const int chunk = rest & (NCH - 1);
    const int b     = rest / NCH;

    float g = gate[0];
    g = fminf(fmaxf(g, 0.0f), 1.0f);
    const float a  = ALPHA;
    const float na = 1.0f - ALPHA;
    const float c2 = 1.0f - 2.0f * g;          // out = g*x + (1-2g)*t

    const int base = (b * L) * CV + c4;        // float4 index of (b, l=0, c4)
    const int l0   = chunk * CH;

    float4 t;
    int lstart;
    if (chunk == 0) {
        // Exact start: t_0 = x_0, and l=0 produces an output.
        t = x[base];
        float4 o;
        o.x = fmaf(g, t.x, c2 * t.x);
        o.y = fmaf(g, t.y, c2 * t.y);
        o.z = fmaf(g, t.z, c2 * t.z);
        o.w = fmaf(g, t.w, c2 * t.w);
        out[base] = o;
        lstart = 1;
    } else {
        // Halo warm-up: seed with x[l0-H], run H-1 recurrence steps.
        t = x[base + (l0 - H) * CV];
#pragma unroll
        for (int l = l0 - H + 1; l < l0; ++l) {
            float4 xv = x[base + l * CV];
            t = ema_step(t, xv, a, na);
        }
        lstart = l0;
    }

#pragma unroll 8
    for (int l = lstart; l < l0 + CH; ++l) {
        float4 xv = x[base + l * CV];
        t = ema_step(t, xv, a, na);
        float4 o;
        o.x = fmaf(g, xv.x, c2 * t.x);
        o.y = fmaf(g, xv.y, c2 * t.y);
        o.z = fmaf(g, xv.z, c2 * t.z);
        o.w = fmaf(g, xv.w, c2 * t.w);
        out[base + l * CV] = o;
    }
}

extern "C" void kernel_launch(void* const* d_in, const int* in_sizes, int n_in,
                              void* d_out, int out_size, void* d_ws, size_t ws_size,
                              hipStream_t stream) {
    const float4* x    = (const float4*)d_in[0];
    const float*  gate = (const float*)d_in[1];
    float4* out        = (float4*)d_out;

    const int total_threads = B * NCH * CV;    // 131072
    const int block = 256;
    const int grid  = total_threads / block;   // 512
    STAR_47605417509306_kernel<<<grid, block, 0, stream>>>(x, gate, out);
}